// Round 6
// baseline (313.881 us; speedup 1.0000x reference)
//
#include <hip/hip_runtime.h>

#define NB 22
#define NFR_B 7499
#define BATCH 32
#define ROWLEN 960000
#define NFTOT (BATCH * NFR_B)

typedef float f2 __attribute__((ext_vector_type(2)));

__constant__ int c_bands[NB] = {0,4,8,12,16,20,24,28,32,40,44,48,52,56,64,72,80,88,96,104,112,128};

// ---- cross-lane primitives (immediate patterns; no index setup) ----
#define XDPP(x, CTRL) __int_as_float(__builtin_amdgcn_update_dpp(0, __float_as_int(x), CTRL, 0xF, 0xF, true))
#define XSWZ(x, PATT) __int_as_float(__builtin_amdgcn_ds_swizzle(__float_as_int(x), PATT))
#define E0S(x) XDPP(x, 0xB1)      // xor 1  (quad_perm)
#define E1S(x) XDPP(x, 0x4E)      // xor 2  (quad_perm)
#define E2S(x) XSWZ(x, 0x101F)    // xor 4  (swizzle BitMode)
#define E3S(x) XDPP(x, 0x128)     // xor 8  (row_ror:8)
#define E4S(x) XSWZ(x, 0x401F)    // xor 16
#define BC32(x, B) XSWZ(x, ((B) << 5))   // broadcast lane B within 32-lane halves (B literal!)

__device__ __forceinline__ float bperm(int addr4, float v) {
    return __int_as_float(__builtin_amdgcn_ds_bpermute(addr4, __float_as_int(v)));
}
__device__ __forceinline__ f2 mk2(float v) { f2 r; r.x = v; r.y = v; return r; }
__device__ __forceinline__ f2 ex0v(f2 v) { f2 r; r.x = E0S(v.x); r.y = E0S(v.y); return r; }
__device__ __forceinline__ f2 ex1v(f2 v) { f2 r; r.x = E1S(v.x); r.y = E1S(v.y); return r; }
__device__ __forceinline__ f2 ex2v(f2 v) { f2 r; r.x = E2S(v.x); r.y = E2S(v.y); return r; }
__device__ __forceinline__ f2 ex3v(f2 v) { f2 r; r.x = E3S(v.x); r.y = E3S(v.y); return r; }
__device__ __forceinline__ f2 ex4v(f2 v) { f2 r; r.x = E4S(v.x); r.y = E4S(v.y); return r; }
__device__ __forceinline__ f2 bpermv(int addr4, f2 v) {
    f2 r; r.x = bperm(addr4, v.x); r.y = bperm(addr4, v.y); return r;
}

// packed select-free stage: res = W1*x + W2*e
#define PSTAGE(S, EXF)                                                    \
  { const f2 exr_a = EXF(ar2), exi_a = EXF(ai2);                          \
    const f2 exr_b = EXF(br2), exi_b = EXF(bi2);                          \
    const f2 w1r = mk2(W1r[S]), w1i = mk2(W1i[S]);                        \
    const f2 w2r = mk2(W2r[S]), w2i = mk2(W2i[S]);                        \
    const f2 nar = w1r*ar2 - w1i*ai2 + w2r*exr_a - w2i*exi_a;             \
    const f2 nai = w1r*ai2 + w1i*ar2 + w2r*exi_a + w2i*exr_a;             \
    const f2 nbr = w1r*br2 - w1i*bi2 + w2r*exr_b - w2i*exi_b;             \
    const f2 nbi = w1r*bi2 + w1i*br2 + w2r*exi_b + w2i*exr_b;             \
    ar2 = nar; ai2 = nai; br2 = nbr; bi2 = nbi; }

// DCT symmetric pair with LITERAL band index B: acc += coef[B]*(z[B] + sOc*z[21-B])
#define DCTPAIR(B, ACC)                                                   \
  { const float zlo = BC32(Z, B);                                         \
    const float zhi = BC32(Z, 21 - (B));                                  \
    ACC = fmaf(coef[B], fmaf(sOc, zhi, zlo), ACC); }

__global__ __launch_bounds__(256, 7)
void feat_kernel(const float* __restrict__ x, float* __restrict__ out) {
    const int lane = threadIdx.x & 63;
    const int wid  = threadIdx.x >> 6;
    const int gwave  = blockIdx.x * (blockDim.x >> 6) + wid;
    const int nwaves = gridDim.x * (blockDim.x >> 6);

    const float PI = 3.14159265358979323846f;

    // 7-bit bit-reversal of lane (bit6 = 0 -> r even)
    const int r = (int)(__brev((unsigned)lane) >> 25);

    float winv[4];
    #pragma unroll
    for (int j = 0; j < 4; ++j) winv[j] = sinf(PI * (float)(2 * r + j) / 256.0f);

    // select-free butterfly constants
    float W1r[6], W1i[6], W2r[6], W2i[6];
    #pragma unroll
    for (int s = 1; s < 6; ++s) {
        const int m = 1 << s;
        const float ang = -PI * (float)(lane & (m - 1)) / (float)m;
        const float wr = cosf(ang), wi = sinf(ang);
        const bool up = ((lane >> s) & 1) != 0;
        W1r[s] = up ? -wr : 1.0f;
        W1i[s] = up ? -wi : 0.0f;
        W2r[s] = up ? 1.0f : wr;
        W2i[s] = up ? 0.0f : wi;
    }
    const float sgn0 = (lane & 1) ? -1.0f : 1.0f;     // stage 0 (w = 1)
    const float w6r = cosf(-PI * (float)lane / 64.0f);
    const float w6i = sinf(-PI * (float)lane / 64.0f);
    const float c1 = cosf(PI * (float)lane / 128.0f);
    const float s1 = sinf(PI * (float)lane / 128.0f);

    // ---- band segmentation constants ----
    int seg1 = 0;
    for (int j = 1; j < 14; ++j) if (lane >= c_bands[j]) seg1 = j;
    const int wd1 = c_bands[seg1 + 1] - c_bands[seg1];
    const float a1 = (float)(lane - c_bands[seg1]) / (float)wd1;
    const float m8 = (wd1 == 8) ? 1.0f : 0.0f;
    const int bin2 = lane + 64;
    int seg2 = 14;
    for (int j = 15; j < 21; ++j) if (bin2 >= c_bands[j]) seg2 = j;
    const int wd2 = c_bands[seg2 + 1] - c_bands[seg2];
    const float a2 = (float)(bin2 - c_bands[seg2]) / (float)wd2;
    const float m16 = (seg2 == 20) ? 1.0f : 0.0f;

    // gather byte-indices (hoisted once)
    const int c = lane;
    int idxA = 0; bool selA1 = true;
    if (c >= 1 && c <= 21) {
        if (c - 1 <= 13) { idxA = c_bands[c - 1]; selA1 = true; }
        else             { idxA = c_bands[c - 1] - 64; selA1 = false; }
    }
    int idxD = 0; bool selD1 = true;
    if (c <= 20) {
        if (c <= 13) { idxD = c_bands[c]; selD1 = true; }
        else         { idxD = c_bands[c] - 64; selD1 = false; }
    }
    const int bpA = idxA << 2;
    const int bpD = idxD << 2;
    const int bpHerm = (((64 - lane) & 63) << 2);
    const int bpX32  = ((lane ^ 32) << 2);

    // DCT: symmetric-pair form. coef[21-b] = (-1)^oc * coef[b]
    const int oc = lane & 31;
    float coef[11];
    {
        const float norm = 0.30102999566398120f * sqrtf(2.0f / (float)NB) *
                           ((oc == 0) ? 0.70710678118654752f : 1.0f);
        #pragma unroll
        for (int b = 0; b < 11; ++b)
            coef[b] = norm * cosf(PI / (float)NB * ((float)b + 0.5f) * (float)oc);
    }
    const float sOc = (oc & 1) ? -1.0f : 1.0f;
    // pw scaled x4 (dropped 0.5 in E/O): only row oc=0 has nonzero coef sum
    const float accInit = (oc == 0) ? (-2.0f * 0.30102999566398120f * sqrtf(22.0f)) : 0.0f;

    // even-sized contiguous frame chunk per wave
    const int chunk = (((NFTOT + nwaves - 1) / nwaves) + 1) & ~1;
    int f0 = gwave * chunk;
    if (f0 >= NFTOT) return;
    int f1 = f0 + chunk; if (f1 > NFTOT) f1 = NFTOT;
    const int f0u = __builtin_amdgcn_readfirstlane(f0);
    const int f1u = __builtin_amdgcn_readfirstlane(f1);

    int bb = f0u / NFR_B;
    int t0 = f0u - bb * NFR_B;
    const float* p0 = x + (size_t)bb * ROWLEN + (size_t)t0 * 128;
    int t1 = t0 + 1;
    const float* p1 = p0 + 128;
    if (t1 == NFR_B) { t1 = 0; p1 += 128; }

    float* ob = out + (size_t)f0u * NB + ((lane < 32) ? oc : (NB + oc));

    float4 v0 = *(const float4*)(p0 + 2 * r);
    float4 v1 = *(const float4*)(p1 + 2 * r);

    for (int f = f0u; f < f1u; f += 2) {
        // next-pair pointers + prefetch
        int nt0 = t1 + 1; const float* np0 = p1 + 128;
        if (nt0 == NFR_B) { nt0 = 0; np0 += 128; }
        int nt1 = nt0 + 1; const float* np1 = np0 + 128;
        if (nt1 == NFR_B) { nt1 = 0; np1 += 128; }
        float4 nv0 = v0, nv1 = v1;
        if (f + 2 < f1u) {
            nv0 = *(const float4*)(np0 + 2 * r);
            nv1 = *(const float4*)(np1 + 2 * r);
        }

        // window + pack (frame0 in .x, frame1 in .y)
        f2 ar2 = { v0.x * winv[0], v1.x * winv[0] };
        f2 ai2 = { v0.y * winv[1], v1.y * winv[1] };
        f2 br2 = { v0.z * winv[2], v1.z * winv[2] };
        f2 bi2 = { v0.w * winv[3], v1.w * winv[3] };

        // stage 0: w = 1 -> res = sgn*x + e
        {
            const f2 e_ar = ex0v(ar2), e_ai = ex0v(ai2);
            const f2 e_br = ex0v(br2), e_bi = ex0v(bi2);
            const f2 s2 = mk2(sgn0);
            ar2 = s2 * ar2 + e_ar;  ai2 = s2 * ai2 + e_ai;
            br2 = s2 * br2 + e_br;  bi2 = s2 * bi2 + e_bi;
        }
        PSTAGE(1, ex1v)
        PSTAGE(2, ex2v)
        PSTAGE(3, ex3v)
        PSTAGE(4, ex4v)
        // stage 5: xor 32 via hoisted bpermute index
        {
            const f2 exr_a = bpermv(bpX32, ar2), exi_a = bpermv(bpX32, ai2);
            const f2 exr_b = bpermv(bpX32, br2), exi_b = bpermv(bpX32, bi2);
            const f2 w1r = mk2(W1r[5]), w1i = mk2(W1i[5]);
            const f2 w2r = mk2(W2r[5]), w2i = mk2(W2i[5]);
            const f2 nar = w1r*ar2 - w1i*ai2 + w2r*exr_a - w2i*exi_a;
            const f2 nai = w1r*ai2 + w1i*ar2 + w2r*exi_a + w2i*exr_a;
            const f2 nbr = w1r*br2 - w1i*bi2 + w2r*exr_b - w2i*exi_b;
            const f2 nbi = w1r*bi2 + w1i*br2 + w2r*exi_b + w2i*exr_b;
            ar2 = nar; ai2 = nai; br2 = nbr; bi2 = nbi;
        }

        // span-64 stage (lane-local)
        {
            const f2 tr2 = mk2(w6r) * br2 - mk2(w6i) * bi2;
            const f2 ti2 = mk2(w6r) * bi2 + mk2(w6i) * br2;
            const f2 nar = ar2 + tr2, nai = ai2 + ti2;
            br2 = ar2 - tr2; bi2 = ai2 - ti2;
            ar2 = nar; ai2 = nai;
        }

        // Hermitian unpack (0.5 factors dropped -> pw scaled x4)
        const f2 par2 = bpermv(bpHerm, ar2), pai2 = bpermv(bpHerm, ai2);
        const f2 pbr2 = bpermv(bpHerm, br2), pbi2 = bpermv(bpHerm, bi2);
        const f2 P1r = (lane == 0) ? par2 : pbr2, P1i = (lane == 0) ? pai2 : pbi2;
        const f2 P2r = (lane == 0) ? pbr2 : par2, P2i = (lane == 0) ? pbi2 : pai2;

        f2 Er = ar2 + P1r, Ei = ai2 - P1i;
        f2 Or_ = ar2 - P1r, Oi = ai2 + P1i;
        const f2 X1r = Er + mk2(c1) * Oi - mk2(s1) * Or_;
        const f2 X1i = Ei - mk2(c1) * Or_ - mk2(s1) * Oi;
        const f2 pw1 = X1r * X1r + X1i * X1i;

        Er = br2 + P2r; Ei = bi2 - P2i;
        Or_ = br2 - P2r; Oi = bi2 + P2i;
        const f2 X2r = Er - mk2(s1) * Oi - mk2(c1) * Or_;
        const f2 X2i = Ei + mk2(s1) * Or_ - mk2(c1) * Oi;
        const f2 pw2 = X2r * X2r + X2i * X2i;

        // segmented band reduction
        f2 S1 = pw1, T1 = mk2(a1) * pw1;
        S1 = S1 + ex0v(S1); T1 = T1 + ex0v(T1);
        S1 = S1 + ex1v(S1); T1 = T1 + ex1v(T1);
        S1 = mk2(m8) * ex2v(S1) + S1; T1 = mk2(m8) * ex2v(T1) + T1;
        const f2 D1 = S1 - T1;
        f2 S2 = pw2, T2 = mk2(a2) * pw2;
        S2 = S2 + ex0v(S2); T2 = T2 + ex0v(T2);
        S2 = S2 + ex1v(S2); T2 = T2 + ex1v(T2);
        S2 = S2 + ex2v(S2); T2 = T2 + ex2v(T2);
        S2 = mk2(m16) * ex3v(S2) + S2; T2 = mk2(m16) * ex3v(T2) + T2;
        const f2 D2 = S2 - T2;

        // per-band assembly: band c = A(seg c-1) + D(seg c); edges x2
        const f2 gA1 = bpermv(bpA, T1), gA2 = bpermv(bpA, T2);
        const f2 gD1 = bpermv(bpD, D1), gD2 = bpermv(bpD, D2);
        const f2 A_prev = selA1 ? gA1 : gA2;
        const f2 D_cur  = selD1 ? gD1 : gD2;
        f2 band = A_prev + D_cur;
        if (c == 0)  band = D_cur + D_cur;
        if (c == 21) band = A_prev + A_prev;

        f2 l2;
        l2.x = __log2f(band.x);
        l2.y = __log2f(band.y);

        // lanes 0..31 serve frame0's bands, 32..63 frame1's
        const float hi_sh = bperm(bpX32, l2.y);
        const float Z = (lane < 32) ? l2.x : hi_sh;

        // symmetric-pair DCT (literal indices, two accumulator chains)
        float acc0 = accInit, acc1 = 0.0f;
        DCTPAIR(0, acc0)  DCTPAIR(1, acc1)
        DCTPAIR(2, acc0)  DCTPAIR(3, acc1)
        DCTPAIR(4, acc0)  DCTPAIR(5, acc1)
        DCTPAIR(6, acc0)  DCTPAIR(7, acc1)
        DCTPAIR(8, acc0)  DCTPAIR(9, acc1)
        DCTPAIR(10, acc0)
        if (oc < NB) *ob = acc0 + acc1;

        // advance
        v0 = nv0; v1 = nv1;
        t0 = nt0; t1 = nt1; p0 = np0; p1 = np1;
        ob += 2 * NB;
    }
}

extern "C" void kernel_launch(void* const* d_in, const int* in_sizes, int n_in,
                              void* d_out, int out_size, void* d_ws, size_t ws_size,
                              hipStream_t stream) {
    const float* x = (const float*)d_in[0];
    float* out = (float*)d_out;
    feat_kernel<<<1792, 256, 0, stream>>>(x, out);
}

// Round 7
// 250.898 us; speedup vs baseline: 1.2510x; 1.2510x over previous
//
#include <hip/hip_runtime.h>

#define NB 22
#define NFR_B 7499
#define BATCH 32
#define ROWLEN 960000
#define NFTOT (BATCH * NFR_B)

typedef float f2 __attribute__((ext_vector_type(2)));

__constant__ int c_bands[NB] = {0,4,8,12,16,20,24,28,32,40,44,48,52,56,64,72,80,88,96,104,112,128};

// ---- cross-lane primitives (immediate patterns; no index setup) ----
#define XDPP(x, CTRL) __int_as_float(__builtin_amdgcn_update_dpp(0, __float_as_int(x), CTRL, 0xF, 0xF, true))
#define XSWZ(x, PATT) __int_as_float(__builtin_amdgcn_ds_swizzle(__float_as_int(x), PATT))
#define E0S(x) XDPP(x, 0xB1)      // xor 1  (quad_perm)
#define E1S(x) XDPP(x, 0x4E)      // xor 2  (quad_perm)
#define E2S(x) XSWZ(x, 0x101F)    // xor 4  (swizzle BitMode)
#define E3S(x) XDPP(x, 0x128)     // xor 8  (row_ror:8)
#define E4S(x) XSWZ(x, 0x401F)    // xor 16
#define BC32(x, B) XSWZ(x, ((B) << 5))   // broadcast lane B within 32-lane halves (B literal!)

__device__ __forceinline__ float bperm(int addr4, float v) {
    return __int_as_float(__builtin_amdgcn_ds_bpermute(addr4, __float_as_int(v)));
}
__device__ __forceinline__ f2 mk2(float v) { f2 r; r.x = v; r.y = v; return r; }
__device__ __forceinline__ f2 ex0v(f2 v) { f2 r; r.x = E0S(v.x); r.y = E0S(v.y); return r; }
__device__ __forceinline__ f2 ex1v(f2 v) { f2 r; r.x = E1S(v.x); r.y = E1S(v.y); return r; }
__device__ __forceinline__ f2 ex2v(f2 v) { f2 r; r.x = E2S(v.x); r.y = E2S(v.y); return r; }
__device__ __forceinline__ f2 ex3v(f2 v) { f2 r; r.x = E3S(v.x); r.y = E3S(v.y); return r; }
__device__ __forceinline__ f2 ex4v(f2 v) { f2 r; r.x = E4S(v.x); r.y = E4S(v.y); return r; }
__device__ __forceinline__ f2 bpermv(int addr4, f2 v) {
    f2 r; r.x = bperm(addr4, v.x); r.y = bperm(addr4, v.y); return r;
}

// packed select-free stage: res = W1*x + W2*e
#define PSTAGE(S, EXF)                                                    \
  { const f2 exr_a = EXF(ar2), exi_a = EXF(ai2);                          \
    const f2 exr_b = EXF(br2), exi_b = EXF(bi2);                          \
    const f2 w1r = mk2(W1r[S]), w1i = mk2(W1i[S]);                        \
    const f2 w2r = mk2(W2r[S]), w2i = mk2(W2i[S]);                        \
    const f2 nar = w1r*ar2 - w1i*ai2 + w2r*exr_a - w2i*exi_a;             \
    const f2 nai = w1r*ai2 + w1i*ar2 + w2r*exi_a + w2i*exr_a;             \
    const f2 nbr = w1r*br2 - w1i*bi2 + w2r*exr_b - w2i*exi_b;             \
    const f2 nbi = w1r*bi2 + w1i*br2 + w2r*exi_b + w2i*exr_b;             \
    ar2 = nar; ai2 = nai; br2 = nbr; bi2 = nbi; }

// DCT symmetric pair with LITERAL band index B: acc += coef[B]*(z[B] + sOc*z[21-B])
#define DCTPAIR(B, ACC)                                                   \
  { const float zlo = BC32(Z, B);                                         \
    const float zhi = BC32(Z, 21 - (B));                                  \
    ACC = fmaf(coef[B], fmaf(sOc, zhi, zlo), ACC); }

__global__ __launch_bounds__(256, 6)
void feat_kernel(const float* __restrict__ x, float* __restrict__ out) {
    const int lane = threadIdx.x & 63;
    const int wid  = threadIdx.x >> 6;
    const int gwave  = blockIdx.x * (blockDim.x >> 6) + wid;
    const int nwaves = gridDim.x * (blockDim.x >> 6);

    const float PI = 3.14159265358979323846f;

    // 7-bit bit-reversal of lane (bit6 = 0 -> r even)
    const int r = (int)(__brev((unsigned)lane) >> 25);

    float winv[4];
    #pragma unroll
    for (int j = 0; j < 4; ++j) winv[j] = sinf(PI * (float)(2 * r + j) / 256.0f);

    // select-free butterfly constants
    float W1r[6], W1i[6], W2r[6], W2i[6];
    #pragma unroll
    for (int s = 1; s < 6; ++s) {
        const int m = 1 << s;
        const float ang = -PI * (float)(lane & (m - 1)) / (float)m;
        const float wr = cosf(ang), wi = sinf(ang);
        const bool up = ((lane >> s) & 1) != 0;
        W1r[s] = up ? -wr : 1.0f;
        W1i[s] = up ? -wi : 0.0f;
        W2r[s] = up ? 1.0f : wr;
        W2i[s] = up ? 0.0f : wi;
    }
    const float sgn0 = (lane & 1) ? -1.0f : 1.0f;     // stage 0 (w = 1)
    const float w6r = cosf(-PI * (float)lane / 64.0f);
    const float w6i = sinf(-PI * (float)lane / 64.0f);
    const float c1 = cosf(PI * (float)lane / 128.0f);
    const float s1 = sinf(PI * (float)lane / 128.0f);

    // ---- band segmentation constants ----
    int seg1 = 0;
    for (int j = 1; j < 14; ++j) if (lane >= c_bands[j]) seg1 = j;
    const int wd1 = c_bands[seg1 + 1] - c_bands[seg1];
    const float a1 = (float)(lane - c_bands[seg1]) / (float)wd1;
    const float m8 = (wd1 == 8) ? 1.0f : 0.0f;
    const int bin2 = lane + 64;
    int seg2 = 14;
    for (int j = 15; j < 21; ++j) if (bin2 >= c_bands[j]) seg2 = j;
    const int wd2 = c_bands[seg2 + 1] - c_bands[seg2];
    const float a2 = (float)(bin2 - c_bands[seg2]) / (float)wd2;
    const float m16 = (seg2 == 20) ? 1.0f : 0.0f;

    // gather byte-indices (hoisted once)
    const int c = lane;
    int idxA = 0; bool selA1 = true;
    if (c >= 1 && c <= 21) {
        if (c - 1 <= 13) { idxA = c_bands[c - 1]; selA1 = true; }
        else             { idxA = c_bands[c - 1] - 64; selA1 = false; }
    }
    int idxD = 0; bool selD1 = true;
    if (c <= 20) {
        if (c <= 13) { idxD = c_bands[c]; selD1 = true; }
        else         { idxD = c_bands[c] - 64; selD1 = false; }
    }
    const int bpA = idxA << 2;
    const int bpD = idxD << 2;
    const int bpHerm = (((64 - lane) & 63) << 2);
    const int bpX32  = ((lane ^ 32) << 2);

    // DCT: symmetric-pair form. coef[21-b] = (-1)^oc * coef[b]
    const int oc = lane & 31;
    float coef[11];
    {
        const float norm = 0.30102999566398120f * sqrtf(2.0f / (float)NB) *
                           ((oc == 0) ? 0.70710678118654752f : 1.0f);
        #pragma unroll
        for (int b = 0; b < 11; ++b)
            coef[b] = norm * cosf(PI / (float)NB * ((float)b + 0.5f) * (float)oc);
    }
    const float sOc = (oc & 1) ? -1.0f : 1.0f;
    // pw scaled x4 (dropped 0.5 in E/O): only row oc=0 has nonzero coef sum
    const float accInit = (oc == 0) ? (-2.0f * 0.30102999566398120f * sqrtf(22.0f)) : 0.0f;

    // even-sized contiguous frame chunk per wave
    const int chunk = (((NFTOT + nwaves - 1) / nwaves) + 1) & ~1;
    int f0 = gwave * chunk;
    if (f0 >= NFTOT) return;
    int f1 = f0 + chunk; if (f1 > NFTOT) f1 = NFTOT;
    const int f0u = __builtin_amdgcn_readfirstlane(f0);
    const int f1u = __builtin_amdgcn_readfirstlane(f1);

    int bb = f0u / NFR_B;
    int t0 = f0u - bb * NFR_B;
    const float* p0 = x + (size_t)bb * ROWLEN + (size_t)t0 * 128;
    int t1 = t0 + 1;
    const float* p1 = p0 + 128;
    if (t1 == NFR_B) { t1 = 0; p1 += 128; }

    float* ob = out + (size_t)f0u * NB + ((lane < 32) ? oc : (NB + oc));

    float4 v0 = *(const float4*)(p0 + 2 * r);
    float4 v1 = *(const float4*)(p1 + 2 * r);

    for (int f = f0u; f < f1u; f += 2) {
        // next-pair pointers + prefetch
        int nt0 = t1 + 1; const float* np0 = p1 + 128;
        if (nt0 == NFR_B) { nt0 = 0; np0 += 128; }
        int nt1 = nt0 + 1; const float* np1 = np0 + 128;
        if (nt1 == NFR_B) { nt1 = 0; np1 += 128; }
        float4 nv0 = v0, nv1 = v1;
        if (f + 2 < f1u) {
            nv0 = *(const float4*)(np0 + 2 * r);
            nv1 = *(const float4*)(np1 + 2 * r);
        }

        // window + pack (frame0 in .x, frame1 in .y)
        f2 ar2 = { v0.x * winv[0], v1.x * winv[0] };
        f2 ai2 = { v0.y * winv[1], v1.y * winv[1] };
        f2 br2 = { v0.z * winv[2], v1.z * winv[2] };
        f2 bi2 = { v0.w * winv[3], v1.w * winv[3] };

        // stage 0: w = 1 -> res = sgn*x + e
        {
            const f2 e_ar = ex0v(ar2), e_ai = ex0v(ai2);
            const f2 e_br = ex0v(br2), e_bi = ex0v(bi2);
            const f2 s2 = mk2(sgn0);
            ar2 = s2 * ar2 + e_ar;  ai2 = s2 * ai2 + e_ai;
            br2 = s2 * br2 + e_br;  bi2 = s2 * bi2 + e_bi;
        }
        PSTAGE(1, ex1v)
        PSTAGE(2, ex2v)
        PSTAGE(3, ex3v)
        PSTAGE(4, ex4v)
        // stage 5: xor 32 via hoisted bpermute index
        {
            const f2 exr_a = bpermv(bpX32, ar2), exi_a = bpermv(bpX32, ai2);
            const f2 exr_b = bpermv(bpX32, br2), exi_b = bpermv(bpX32, bi2);
            const f2 w1r = mk2(W1r[5]), w1i = mk2(W1i[5]);
            const f2 w2r = mk2(W2r[5]), w2i = mk2(W2i[5]);
            const f2 nar = w1r*ar2 - w1i*ai2 + w2r*exr_a - w2i*exi_a;
            const f2 nai = w1r*ai2 + w1i*ar2 + w2r*exi_a + w2i*exr_a;
            const f2 nbr = w1r*br2 - w1i*bi2 + w2r*exr_b - w2i*exi_b;
            const f2 nbi = w1r*bi2 + w1i*br2 + w2r*exi_b + w2i*exr_b;
            ar2 = nar; ai2 = nai; br2 = nbr; bi2 = nbi;
        }

        // span-64 stage (lane-local)
        {
            const f2 tr2 = mk2(w6r) * br2 - mk2(w6i) * bi2;
            const f2 ti2 = mk2(w6r) * bi2 + mk2(w6i) * br2;
            const f2 nar = ar2 + tr2, nai = ai2 + ti2;
            br2 = ar2 - tr2; bi2 = ai2 - ti2;
            ar2 = nar; ai2 = nai;
        }

        // Hermitian unpack (0.5 factors dropped -> pw scaled x4)
        const f2 par2 = bpermv(bpHerm, ar2), pai2 = bpermv(bpHerm, ai2);
        const f2 pbr2 = bpermv(bpHerm, br2), pbi2 = bpermv(bpHerm, bi2);
        const f2 P1r = (lane == 0) ? par2 : pbr2, P1i = (lane == 0) ? pai2 : pbi2;
        const f2 P2r = (lane == 0) ? pbr2 : par2, P2i = (lane == 0) ? pbi2 : pai2;

        f2 Er = ar2 + P1r, Ei = ai2 - P1i;
        f2 Or_ = ar2 - P1r, Oi = ai2 + P1i;
        const f2 X1r = Er + mk2(c1) * Oi - mk2(s1) * Or_;
        const f2 X1i = Ei - mk2(c1) * Or_ - mk2(s1) * Oi;
        const f2 pw1 = X1r * X1r + X1i * X1i;

        Er = br2 + P2r; Ei = bi2 - P2i;
        Or_ = br2 - P2r; Oi = bi2 + P2i;
        const f2 X2r = Er - mk2(s1) * Oi - mk2(c1) * Or_;
        const f2 X2i = Ei + mk2(s1) * Or_ - mk2(c1) * Oi;
        const f2 pw2 = X2r * X2r + X2i * X2i;

        // segmented band reduction
        f2 S1 = pw1, T1 = mk2(a1) * pw1;
        S1 = S1 + ex0v(S1); T1 = T1 + ex0v(T1);
        S1 = S1 + ex1v(S1); T1 = T1 + ex1v(T1);
        S1 = mk2(m8) * ex2v(S1) + S1; T1 = mk2(m8) * ex2v(T1) + T1;
        const f2 D1 = S1 - T1;
        f2 S2 = pw2, T2 = mk2(a2) * pw2;
        S2 = S2 + ex0v(S2); T2 = T2 + ex0v(T2);
        S2 = S2 + ex1v(S2); T2 = T2 + ex1v(T2);
        S2 = S2 + ex2v(S2); T2 = T2 + ex2v(T2);
        S2 = mk2(m16) * ex3v(S2) + S2; T2 = mk2(m16) * ex3v(T2) + T2;
        const f2 D2 = S2 - T2;

        // per-band assembly: band c = A(seg c-1) + D(seg c); edges x2
        const f2 gA1 = bpermv(bpA, T1), gA2 = bpermv(bpA, T2);
        const f2 gD1 = bpermv(bpD, D1), gD2 = bpermv(bpD, D2);
        const f2 A_prev = selA1 ? gA1 : gA2;
        const f2 D_cur  = selD1 ? gD1 : gD2;
        f2 band = A_prev + D_cur;
        if (c == 0)  band = D_cur + D_cur;
        if (c == 21) band = A_prev + A_prev;

        f2 l2;
        l2.x = __log2f(band.x);
        l2.y = __log2f(band.y);

        // lanes 0..31 serve frame0's bands, 32..63 frame1's
        const float hi_sh = bperm(bpX32, l2.y);
        const float Z = (lane < 32) ? l2.x : hi_sh;

        // symmetric-pair DCT (literal indices, two accumulator chains)
        float acc0 = accInit, acc1 = 0.0f;
        DCTPAIR(0, acc0)  DCTPAIR(1, acc1)
        DCTPAIR(2, acc0)  DCTPAIR(3, acc1)
        DCTPAIR(4, acc0)  DCTPAIR(5, acc1)
        DCTPAIR(6, acc0)  DCTPAIR(7, acc1)
        DCTPAIR(8, acc0)  DCTPAIR(9, acc1)
        DCTPAIR(10, acc0)
        if (oc < NB) *ob = acc0 + acc1;

        // advance
        v0 = nv0; v1 = nv1;
        t0 = nt0; t1 = nt1; p0 = np0; p1 = np1;
        ob += 2 * NB;
    }
}

extern "C" void kernel_launch(void* const* d_in, const int* in_sizes, int n_in,
                              void* d_out, int out_size, void* d_ws, size_t ws_size,
                              hipStream_t stream) {
    const float* x = (const float*)d_in[0];
    float* out = (float*)d_out;
    feat_kernel<<<1536, 256, 0, stream>>>(x, out);
}

// Round 8
// 89.686 us; speedup vs baseline: 3.4998x; 2.7975x over previous
//
#include <hip/hip_runtime.h>

#define NB 22
#define NFR_B 7499
#define BATCH 32
#define ROWLEN 960000
#define NFTOT (BATCH * NFR_B)

typedef float f2 __attribute__((ext_vector_type(2)));

__constant__ int c_bands[NB] = {0,4,8,12,16,20,24,28,32,40,44,48,52,56,64,72,80,88,96,104,112,128};

// ---- cross-lane primitives (immediate patterns; no index setup) ----
#define XDPP(x, CTRL) __int_as_float(__builtin_amdgcn_update_dpp(0, __float_as_int(x), CTRL, 0xF, 0xF, true))
#define XSWZ(x, PATT) __int_as_float(__builtin_amdgcn_ds_swizzle(__float_as_int(x), PATT))
#define E0S(x) XDPP(x, 0xB1)      // xor 1  (quad_perm)
#define E1S(x) XDPP(x, 0x4E)      // xor 2  (quad_perm)
#define E2S(x) XSWZ(x, 0x101F)    // xor 4  (swizzle BitMode)
#define E3S(x) XDPP(x, 0x128)     // xor 8  (row_ror:8)
#define E4S(x) XSWZ(x, 0x401F)    // xor 16
#define BC32(x, B) XSWZ(x, ((B) << 5))   // broadcast lane B within 32-lane halves (B literal!)

__device__ __forceinline__ float bperm(int addr4, float v) {
    return __int_as_float(__builtin_amdgcn_ds_bpermute(addr4, __float_as_int(v)));
}
__device__ __forceinline__ f2 mk2(float v) { f2 r; r.x = v; r.y = v; return r; }
__device__ __forceinline__ f2 ex0v(f2 v) { f2 r; r.x = E0S(v.x); r.y = E0S(v.y); return r; }
__device__ __forceinline__ f2 ex1v(f2 v) { f2 r; r.x = E1S(v.x); r.y = E1S(v.y); return r; }
__device__ __forceinline__ f2 ex2v(f2 v) { f2 r; r.x = E2S(v.x); r.y = E2S(v.y); return r; }
__device__ __forceinline__ f2 ex3v(f2 v) { f2 r; r.x = E3S(v.x); r.y = E3S(v.y); return r; }
__device__ __forceinline__ f2 ex4v(f2 v) { f2 r; r.x = E4S(v.x); r.y = E4S(v.y); return r; }
__device__ __forceinline__ f2 bpermv(int addr4, f2 v) {
    f2 r; r.x = bperm(addr4, v.x); r.y = bperm(addr4, v.y); return r;
}

// packed select-free stage: res = W1*x + W2*e
#define PSTAGE(S, EXF)                                                    \
  { const f2 exr_a = EXF(ar2), exi_a = EXF(ai2);                          \
    const f2 exr_b = EXF(br2), exi_b = EXF(bi2);                          \
    const f2 w1r = mk2(W1r[S]), w1i = mk2(W1i[S]);                        \
    const f2 w2r = mk2(W2r[S]), w2i = mk2(W2i[S]);                        \
    const f2 nar = w1r*ar2 - w1i*ai2 + w2r*exr_a - w2i*exi_a;             \
    const f2 nai = w1r*ai2 + w1i*ar2 + w2r*exi_a + w2i*exr_a;             \
    const f2 nbr = w1r*br2 - w1i*bi2 + w2r*exr_b - w2i*exi_b;             \
    const f2 nbi = w1r*bi2 + w1i*br2 + w2r*exi_b + w2i*exr_b;             \
    ar2 = nar; ai2 = nai; br2 = nbr; bi2 = nbi; }

// DCT symmetric pair with LITERAL band index B: acc += coef[B]*(z[B] + sOc*z[21-B])
#define DCTPAIR(B, ACC)                                                   \
  { const float zlo = BC32(Z, B);                                         \
    const float zhi = BC32(Z, 21 - (B));                                  \
    ACC = fmaf(coef[B], fmaf(sOc, zhi, zlo), ACC); }

__global__ __launch_bounds__(256, 4)
void feat_kernel(const float* __restrict__ x, float* __restrict__ out) {
    const int lane = threadIdx.x & 63;
    const int wid  = threadIdx.x >> 6;
    const int gwave  = blockIdx.x * (blockDim.x >> 6) + wid;
    const int nwaves = gridDim.x * (blockDim.x >> 6);

    const float PI = 3.14159265358979323846f;

    // 7-bit bit-reversal of lane (bit6 = 0 -> r even)
    const int r = (int)(__brev((unsigned)lane) >> 25);

    float winv[4];
    #pragma unroll
    for (int j = 0; j < 4; ++j) winv[j] = sinf(PI * (float)(2 * r + j) / 256.0f);

    // select-free butterfly constants
    float W1r[6], W1i[6], W2r[6], W2i[6];
    #pragma unroll
    for (int s = 1; s < 6; ++s) {
        const int m = 1 << s;
        const float ang = -PI * (float)(lane & (m - 1)) / (float)m;
        const float wr = cosf(ang), wi = sinf(ang);
        const bool up = ((lane >> s) & 1) != 0;
        W1r[s] = up ? -wr : 1.0f;
        W1i[s] = up ? -wi : 0.0f;
        W2r[s] = up ? 1.0f : wr;
        W2i[s] = up ? 0.0f : wi;
    }
    const float sgn0 = (lane & 1) ? -1.0f : 1.0f;     // stage 0 (w = 1)
    const float w6r = cosf(-PI * (float)lane / 64.0f);
    const float w6i = sinf(-PI * (float)lane / 64.0f);
    const float c1 = cosf(PI * (float)lane / 128.0f);
    const float s1 = sinf(PI * (float)lane / 128.0f);

    // ---- band segmentation constants ----
    int seg1 = 0;
    for (int j = 1; j < 14; ++j) if (lane >= c_bands[j]) seg1 = j;
    const int wd1 = c_bands[seg1 + 1] - c_bands[seg1];
    const float a1 = (float)(lane - c_bands[seg1]) / (float)wd1;
    const float m8 = (wd1 == 8) ? 1.0f : 0.0f;
    const int bin2 = lane + 64;
    int seg2 = 14;
    for (int j = 15; j < 21; ++j) if (bin2 >= c_bands[j]) seg2 = j;
    const int wd2 = c_bands[seg2 + 1] - c_bands[seg2];
    const float a2 = (float)(bin2 - c_bands[seg2]) / (float)wd2;
    const float m16 = (seg2 == 20) ? 1.0f : 0.0f;

    // gather byte-indices (hoisted once)
    const int c = lane;
    int idxA = 0; bool selA1 = true;
    if (c >= 1 && c <= 21) {
        if (c - 1 <= 13) { idxA = c_bands[c - 1]; selA1 = true; }
        else             { idxA = c_bands[c - 1] - 64; selA1 = false; }
    }
    int idxD = 0; bool selD1 = true;
    if (c <= 20) {
        if (c <= 13) { idxD = c_bands[c]; selD1 = true; }
        else         { idxD = c_bands[c] - 64; selD1 = false; }
    }
    const int bpA = idxA << 2;
    const int bpD = idxD << 2;
    const int bpHerm = (((64 - lane) & 63) << 2);
    const int bpX32  = ((lane ^ 32) << 2);

    // DCT: symmetric-pair form. coef[21-b] = (-1)^oc * coef[b]
    const int oc = lane & 31;
    float coef[11];
    {
        const float norm = 0.30102999566398120f * sqrtf(2.0f / (float)NB) *
                           ((oc == 0) ? 0.70710678118654752f : 1.0f);
        #pragma unroll
        for (int b = 0; b < 11; ++b)
            coef[b] = norm * cosf(PI / (float)NB * ((float)b + 0.5f) * (float)oc);
    }
    const float sOc = (oc & 1) ? -1.0f : 1.0f;
    // pw scaled x4 (dropped 0.5 in E/O): only row oc=0 has nonzero coef sum
    const float accInit = (oc == 0) ? (-2.0f * 0.30102999566398120f * sqrtf(22.0f)) : 0.0f;

    // even-sized contiguous frame chunk per wave
    const int chunk = (((NFTOT + nwaves - 1) / nwaves) + 1) & ~1;
    int f0 = gwave * chunk;
    if (f0 >= NFTOT) return;
    int f1 = f0 + chunk; if (f1 > NFTOT) f1 = NFTOT;
    const int f0u = __builtin_amdgcn_readfirstlane(f0);
    const int f1u = __builtin_amdgcn_readfirstlane(f1);

    int bb = f0u / NFR_B;
    int t0 = f0u - bb * NFR_B;
    const float* p0 = x + (size_t)bb * ROWLEN + (size_t)t0 * 128;
    int t1 = t0 + 1;
    const float* p1 = p0 + 128;
    if (t1 == NFR_B) { t1 = 0; p1 += 128; }

    float* ob = out + (size_t)f0u * NB + ((lane < 32) ? oc : (NB + oc));

    float4 v0 = *(const float4*)(p0 + 2 * r);
    float4 v1 = *(const float4*)(p1 + 2 * r);

    for (int f = f0u; f < f1u; f += 2) {
        // next-pair pointers + prefetch
        int nt0 = t1 + 1; const float* np0 = p1 + 128;
        if (nt0 == NFR_B) { nt0 = 0; np0 += 128; }
        int nt1 = nt0 + 1; const float* np1 = np0 + 128;
        if (nt1 == NFR_B) { nt1 = 0; np1 += 128; }
        float4 nv0 = v0, nv1 = v1;
        if (f + 2 < f1u) {
            nv0 = *(const float4*)(np0 + 2 * r);
            nv1 = *(const float4*)(np1 + 2 * r);
        }

        // window + pack (frame0 in .x, frame1 in .y)
        f2 ar2 = { v0.x * winv[0], v1.x * winv[0] };
        f2 ai2 = { v0.y * winv[1], v1.y * winv[1] };
        f2 br2 = { v0.z * winv[2], v1.z * winv[2] };
        f2 bi2 = { v0.w * winv[3], v1.w * winv[3] };

        // stage 0: w = 1 -> res = sgn*x + e
        {
            const f2 e_ar = ex0v(ar2), e_ai = ex0v(ai2);
            const f2 e_br = ex0v(br2), e_bi = ex0v(bi2);
            const f2 s2 = mk2(sgn0);
            ar2 = s2 * ar2 + e_ar;  ai2 = s2 * ai2 + e_ai;
            br2 = s2 * br2 + e_br;  bi2 = s2 * bi2 + e_bi;
        }
        PSTAGE(1, ex1v)
        PSTAGE(2, ex2v)
        PSTAGE(3, ex3v)
        PSTAGE(4, ex4v)
        // stage 5: xor 32 via hoisted bpermute index
        {
            const f2 exr_a = bpermv(bpX32, ar2), exi_a = bpermv(bpX32, ai2);
            const f2 exr_b = bpermv(bpX32, br2), exi_b = bpermv(bpX32, bi2);
            const f2 w1r = mk2(W1r[5]), w1i = mk2(W1i[5]);
            const f2 w2r = mk2(W2r[5]), w2i = mk2(W2i[5]);
            const f2 nar = w1r*ar2 - w1i*ai2 + w2r*exr_a - w2i*exi_a;
            const f2 nai = w1r*ai2 + w1i*ar2 + w2r*exi_a + w2i*exr_a;
            const f2 nbr = w1r*br2 - w1i*bi2 + w2r*exr_b - w2i*exi_b;
            const f2 nbi = w1r*bi2 + w1i*br2 + w2r*exi_b + w2i*exr_b;
            ar2 = nar; ai2 = nai; br2 = nbr; bi2 = nbi;
        }

        // span-64 stage (lane-local)
        {
            const f2 tr2 = mk2(w6r) * br2 - mk2(w6i) * bi2;
            const f2 ti2 = mk2(w6r) * bi2 + mk2(w6i) * br2;
            const f2 nar = ar2 + tr2, nai = ai2 + ti2;
            br2 = ar2 - tr2; bi2 = ai2 - ti2;
            ar2 = nar; ai2 = nai;
        }

        // Hermitian unpack (0.5 factors dropped -> pw scaled x4)
        const f2 par2 = bpermv(bpHerm, ar2), pai2 = bpermv(bpHerm, ai2);
        const f2 pbr2 = bpermv(bpHerm, br2), pbi2 = bpermv(bpHerm, bi2);
        const f2 P1r = (lane == 0) ? par2 : pbr2, P1i = (lane == 0) ? pai2 : pbi2;
        const f2 P2r = (lane == 0) ? pbr2 : par2, P2i = (lane == 0) ? pbi2 : pai2;

        f2 Er = ar2 + P1r, Ei = ai2 - P1i;
        f2 Or_ = ar2 - P1r, Oi = ai2 + P1i;
        const f2 X1r = Er + mk2(c1) * Oi - mk2(s1) * Or_;
        const f2 X1i = Ei - mk2(c1) * Or_ - mk2(s1) * Oi;
        const f2 pw1 = X1r * X1r + X1i * X1i;

        Er = br2 + P2r; Ei = bi2 - P2i;
        Or_ = br2 - P2r; Oi = bi2 + P2i;
        const f2 X2r = Er - mk2(s1) * Oi - mk2(c1) * Or_;
        const f2 X2i = Ei + mk2(s1) * Or_ - mk2(c1) * Oi;
        const f2 pw2 = X2r * X2r + X2i * X2i;

        // segmented band reduction
        f2 S1 = pw1, T1 = mk2(a1) * pw1;
        S1 = S1 + ex0v(S1); T1 = T1 + ex0v(T1);
        S1 = S1 + ex1v(S1); T1 = T1 + ex1v(T1);
        S1 = mk2(m8) * ex2v(S1) + S1; T1 = mk2(m8) * ex2v(T1) + T1;
        const f2 D1 = S1 - T1;
        f2 S2 = pw2, T2 = mk2(a2) * pw2;
        S2 = S2 + ex0v(S2); T2 = T2 + ex0v(T2);
        S2 = S2 + ex1v(S2); T2 = T2 + ex1v(T2);
        S2 = S2 + ex2v(S2); T2 = T2 + ex2v(T2);
        S2 = mk2(m16) * ex3v(S2) + S2; T2 = mk2(m16) * ex3v(T2) + T2;
        const f2 D2 = S2 - T2;

        // per-band assembly: band c = A(seg c-1) + D(seg c); edges x2
        const f2 gA1 = bpermv(bpA, T1), gA2 = bpermv(bpA, T2);
        const f2 gD1 = bpermv(bpD, D1), gD2 = bpermv(bpD, D2);
        const f2 A_prev = selA1 ? gA1 : gA2;
        const f2 D_cur  = selD1 ? gD1 : gD2;
        f2 band = A_prev + D_cur;
        if (c == 0)  band = D_cur + D_cur;
        if (c == 21) band = A_prev + A_prev;

        f2 l2;
        l2.x = __log2f(band.x);
        l2.y = __log2f(band.y);

        // lanes 0..31 serve frame0's bands, 32..63 frame1's
        const float hi_sh = bperm(bpX32, l2.y);
        const float Z = (lane < 32) ? l2.x : hi_sh;

        // symmetric-pair DCT (literal indices, two accumulator chains)
        float acc0 = accInit, acc1 = 0.0f;
        DCTPAIR(0, acc0)  DCTPAIR(1, acc1)
        DCTPAIR(2, acc0)  DCTPAIR(3, acc1)
        DCTPAIR(4, acc0)  DCTPAIR(5, acc1)
        DCTPAIR(6, acc0)  DCTPAIR(7, acc1)
        DCTPAIR(8, acc0)  DCTPAIR(9, acc1)
        DCTPAIR(10, acc0)
        if (oc < NB) *ob = acc0 + acc1;

        // advance
        v0 = nv0; v1 = nv1;
        t0 = nt0; t1 = nt1; p0 = np0; p1 = np1;
        ob += 2 * NB;
    }
}

extern "C" void kernel_launch(void* const* d_in, const int* in_sizes, int n_in,
                              void* d_out, int out_size, void* d_ws, size_t ws_size,
                              hipStream_t stream) {
    const float* x = (const float*)d_in[0];
    float* out = (float*)d_out;
    feat_kernel<<<1792, 256, 0, stream>>>(x, out);
}

// Round 12
// 84.494 us; speedup vs baseline: 3.7148x; 1.0614x over previous
//
#include <hip/hip_runtime.h>

#define NB 22
#define NFR_B 7499
#define BATCH 32
#define ROWLEN 960000
#define NFTOT (BATCH * NFR_B)

typedef float f2 __attribute__((ext_vector_type(2)));

__constant__ int c_bands[NB] = {0,4,8,12,16,20,24,28,32,40,44,48,52,56,64,72,80,88,96,104,112,128};

// ---- cross-lane primitives ----
#define XDPP(x, CTRL) __int_as_float(__builtin_amdgcn_update_dpp(0, __float_as_int(x), CTRL, 0xF, 0xF, true))
#define XSWZ(x, PATT) __int_as_float(__builtin_amdgcn_ds_swizzle(__float_as_int(x), PATT))
#define E0S(x) XDPP(x, 0xB1)      // xor 1  (quad_perm)
#define E1S(x) XDPP(x, 0x4E)      // xor 2  (quad_perm)
#define E2S(x) XSWZ(x, 0x101F)    // xor 4  (swizzle BitMode)
#define E3S(x) XDPP(x, 0x128)     // xor 8  (row_ror:8)
#define BC32(x, B) XSWZ(x, ((B) << 5))   // broadcast lane B within 32-lane halves (B literal!)

__device__ __forceinline__ float bperm(int addr4, float v) {
    return __int_as_float(__builtin_amdgcn_ds_bpermute(addr4, __float_as_int(v)));
}
// permlane self-swap via BUILTIN (compiler handles reg allocation + hazards):
// A = lo-group broadcast, B = hi-group broadcast (VALU pipe, no DS traffic)
struct fpair { float A, B; };
__device__ __forceinline__ fpair bh16(float v) {
    const unsigned u = __float_as_uint(v);
    const auto p = __builtin_amdgcn_permlane16_swap(u, u, false, false);
    fpair r; r.A = __uint_as_float(p[0]); r.B = __uint_as_float(p[1]); return r;
}
__device__ __forceinline__ fpair bh32(float v) {
    const unsigned u = __float_as_uint(v);
    const auto p = __builtin_amdgcn_permlane32_swap(u, u, false, false);
    fpair r; r.A = __uint_as_float(p[0]); r.B = __uint_as_float(p[1]); return r;
}
__device__ __forceinline__ f2 mk2(float v) { f2 r; r.x = v; r.y = v; return r; }
__device__ __forceinline__ f2 ex0v(f2 v) { f2 r; r.x = E0S(v.x); r.y = E0S(v.y); return r; }
__device__ __forceinline__ f2 ex1v(f2 v) { f2 r; r.x = E1S(v.x); r.y = E1S(v.y); return r; }
__device__ __forceinline__ f2 ex2v(f2 v) { f2 r; r.x = E2S(v.x); r.y = E2S(v.y); return r; }
__device__ __forceinline__ f2 ex3v(f2 v) { f2 r; r.x = E3S(v.x); r.y = E3S(v.y); return r; }
__device__ __forceinline__ f2 bpermv(int addr4, f2 v) {
    f2 r; r.x = bperm(addr4, v.x); r.y = bperm(addr4, v.y); return r;
}

// packed select-free stage: res = W1*x + W2*e
#define PSTAGE(S, EXF)                                                    \
  { const f2 exr_a = EXF(ar2), exi_a = EXF(ai2);                          \
    const f2 exr_b = EXF(br2), exi_b = EXF(bi2);                          \
    const f2 w1r = mk2(W1r[S]), w1i = mk2(W1i[S]);                        \
    const f2 w2r = mk2(W2r[S]), w2i = mk2(W2i[S]);                        \
    const f2 nar = w1r*ar2 - w1i*ai2 + w2r*exr_a - w2i*exi_a;             \
    const f2 nai = w1r*ai2 + w1i*ar2 + w2r*exi_a + w2i*exr_a;             \
    const f2 nbr = w1r*br2 - w1i*bi2 + w2r*exr_b - w2i*exi_b;             \
    const f2 nbi = w1r*bi2 + w1i*br2 + w2r*exi_b + w2i*exr_b;             \
    ar2 = nar; ai2 = nai; br2 = nbr; bi2 = nbi; }

// broadcast-halves stage (permlane, by-value pairs): res = A + Ws*B
#define BHSTAGE(BH, WSR, WSI)                                             \
  { const fpair arx = BH(ar2.x), ary = BH(ar2.y);                         \
    const fpair aix = BH(ai2.x), aiy = BH(ai2.y);                         \
    const fpair brx = BH(br2.x), bry = BH(br2.y);                         \
    const fpair bix = BH(bi2.x), biy = BH(bi2.y);                         \
    const f2 Aar = { arx.A, ary.A }, Bar = { arx.B, ary.B };              \
    const f2 Aai = { aix.A, aiy.A }, Bai = { aix.B, aiy.B };              \
    const f2 Abr = { brx.A, bry.A }, Bbr = { brx.B, bry.B };              \
    const f2 Abi = { bix.A, biy.A }, Bbi = { bix.B, biy.B };              \
    const f2 wr = mk2(WSR), wi = mk2(WSI);                                \
    ar2 = Aar + wr*Bar - wi*Bai;                                          \
    ai2 = Aai + wr*Bai + wi*Bar;                                          \
    br2 = Abr + wr*Bbr - wi*Bbi;                                          \
    bi2 = Abi + wr*Bbi + wi*Bbr; }

// DCT symmetric pair with LITERAL band index B: acc += coef[B]*(z[B] + sOc*z[21-B])
#define DCTPAIR(B, ACC)                                                   \
  { const float zlo = BC32(Z, B);                                         \
    const float zhi = BC32(Z, 21 - (B));                                  \
    ACC = fmaf(coef[B], fmaf(sOc, zhi, zlo), ACC); }

__global__ __launch_bounds__(256, 4)
void feat_kernel(const float* __restrict__ x, float* __restrict__ out) {
    const int lane = threadIdx.x & 63;
    const int wid  = threadIdx.x >> 6;
    const int gwave  = blockIdx.x * (blockDim.x >> 6) + wid;
    const int nwaves = gridDim.x * (blockDim.x >> 6);

    const float PI = 3.14159265358979323846f;

    // 7-bit bit-reversal of lane (bit6 = 0 -> r even)
    const int r = (int)(__brev((unsigned)lane) >> 25);

    float winv[4];
    #pragma unroll
    for (int j = 0; j < 4; ++j) winv[j] = sinf(PI * (float)(2 * r + j) / 256.0f);

    // select-free butterfly constants for DPP stages 1..3
    float W1r[4], W1i[4], W2r[4], W2i[4];
    #pragma unroll
    for (int s = 1; s < 4; ++s) {
        const int m = 1 << s;
        const float ang = -PI * (float)(lane & (m - 1)) / (float)m;
        const float wr = cosf(ang), wi = sinf(ang);
        const bool up = ((lane >> s) & 1) != 0;
        W1r[s] = up ? -wr : 1.0f;
        W1i[s] = up ? -wi : 0.0f;
        W2r[s] = up ? 1.0f : wr;
        W2i[s] = up ? 0.0f : wi;
    }
    const float sgn0 = (lane & 1) ? -1.0f : 1.0f;     // stage 0 (w = 1)
    // broadcast-halves signed twiddles for stages 4 (span16) and 5 (span32)
    const float sg4 = ((lane >> 4) & 1) ? -1.0f : 1.0f;
    const float ang4 = -PI * (float)(lane & 15) / 16.0f;
    const float ws4r = sg4 * cosf(ang4), ws4i = sg4 * sinf(ang4);
    const float sg5 = ((lane >> 5) & 1) ? -1.0f : 1.0f;
    const float ang5 = -PI * (float)(lane & 31) / 32.0f;
    const float ws5r = sg5 * cosf(ang5), ws5i = sg5 * sinf(ang5);

    const float w6r = cosf(-PI * (float)lane / 64.0f);
    const float w6i = sinf(-PI * (float)lane / 64.0f);
    const float c1 = cosf(PI * (float)lane / 128.0f);
    const float s1 = sinf(PI * (float)lane / 128.0f);

    // ---- band segmentation constants ----
    int seg1 = 0;
    for (int j = 1; j < 14; ++j) if (lane >= c_bands[j]) seg1 = j;
    const int wd1 = c_bands[seg1 + 1] - c_bands[seg1];
    const float a1 = (float)(lane - c_bands[seg1]) / (float)wd1;
    const float m8 = (wd1 == 8) ? 1.0f : 0.0f;
    const int bin2 = lane + 64;
    int seg2 = 14;
    for (int j = 15; j < 21; ++j) if (bin2 >= c_bands[j]) seg2 = j;
    const int wd2 = c_bands[seg2 + 1] - c_bands[seg2];
    const float a2 = (float)(bin2 - c_bands[seg2]) / (float)wd2;
    const float m16 = (seg2 == 20) ? 1.0f : 0.0f;

    // gather byte-indices (hoisted once)
    const int c = lane;
    int idxA = 0; bool selA1 = true;
    if (c >= 1 && c <= 21) {
        if (c - 1 <= 13) { idxA = c_bands[c - 1]; selA1 = true; }
        else             { idxA = c_bands[c - 1] - 64; selA1 = false; }
    }
    int idxD = 0; bool selD1 = true;
    if (c <= 20) {
        if (c <= 13) { idxD = c_bands[c]; selD1 = true; }
        else         { idxD = c_bands[c] - 64; selD1 = false; }
    }
    const int bpA = idxA << 2;
    const int bpD = idxD << 2;
    const int bpHerm = (((64 - lane) & 63) << 2);

    // DCT: symmetric-pair form. coef[21-b] = (-1)^oc * coef[b]
    const int oc = lane & 31;
    float coef[11];
    {
        const float norm = 0.30102999566398120f * sqrtf(2.0f / (float)NB) *
                           ((oc == 0) ? 0.70710678118654752f : 1.0f);
        #pragma unroll
        for (int b = 0; b < 11; ++b)
            coef[b] = norm * cosf(PI / (float)NB * ((float)b + 0.5f) * (float)oc);
    }
    const float sOc = (oc & 1) ? -1.0f : 1.0f;
    // pw scaled x4 (dropped 0.5 in E/O): only row oc=0 has nonzero coef sum
    const float accInit = (oc == 0) ? (-2.0f * 0.30102999566398120f * sqrtf(22.0f)) : 0.0f;

    // even-sized contiguous frame chunk per wave
    const int chunk = (((NFTOT + nwaves - 1) / nwaves) + 1) & ~1;
    int f0 = gwave * chunk;
    if (f0 >= NFTOT) return;
    int f1 = f0 + chunk; if (f1 > NFTOT) f1 = NFTOT;
    const int f0u = __builtin_amdgcn_readfirstlane(f0);
    const int f1u = __builtin_amdgcn_readfirstlane(f1);

    int bb = f0u / NFR_B;
    int t0 = f0u - bb * NFR_B;
    const float* p0 = x + (size_t)bb * ROWLEN + (size_t)t0 * 128;
    int t1 = t0 + 1;
    const float* p1 = p0 + 128;
    if (t1 == NFR_B) { t1 = 0; p1 += 128; }

    float* ob = out + (size_t)f0u * NB + ((lane < 32) ? oc : (NB + oc));

    float4 v0 = *(const float4*)(p0 + 2 * r);
    float4 v1 = *(const float4*)(p1 + 2 * r);

    for (int f = f0u; f < f1u; f += 2) {
        // next-pair pointers + prefetch
        int nt0 = t1 + 1; const float* np0 = p1 + 128;
        if (nt0 == NFR_B) { nt0 = 0; np0 += 128; }
        int nt1 = nt0 + 1; const float* np1 = np0 + 128;
        if (nt1 == NFR_B) { nt1 = 0; np1 += 128; }
        float4 nv0 = v0, nv1 = v1;
        if (f + 2 < f1u) {
            nv0 = *(const float4*)(np0 + 2 * r);
            nv1 = *(const float4*)(np1 + 2 * r);
        }

        // window + pack (frame0 in .x, frame1 in .y)
        f2 ar2 = { v0.x * winv[0], v1.x * winv[0] };
        f2 ai2 = { v0.y * winv[1], v1.y * winv[1] };
        f2 br2 = { v0.z * winv[2], v1.z * winv[2] };
        f2 bi2 = { v0.w * winv[3], v1.w * winv[3] };

        // stage 0: w = 1 -> res = sgn*x + e
        {
            const f2 e_ar = ex0v(ar2), e_ai = ex0v(ai2);
            const f2 e_br = ex0v(br2), e_bi = ex0v(bi2);
            const f2 s2 = mk2(sgn0);
            ar2 = s2 * ar2 + e_ar;  ai2 = s2 * ai2 + e_ai;
            br2 = s2 * br2 + e_br;  bi2 = s2 * bi2 + e_bi;
        }
        PSTAGE(1, ex1v)
        PSTAGE(2, ex2v)
        PSTAGE(3, ex3v)
        BHSTAGE(bh16, ws4r, ws4i)   // span 16 via v_permlane16_swap (VALU)
        BHSTAGE(bh32, ws5r, ws5i)   // span 32 via v_permlane32_swap (VALU)

        // span-64 stage (lane-local)
        {
            const f2 tr2 = mk2(w6r) * br2 - mk2(w6i) * bi2;
            const f2 ti2 = mk2(w6r) * bi2 + mk2(w6i) * br2;
            const f2 nar = ar2 + tr2, nai = ai2 + ti2;
            br2 = ar2 - tr2; bi2 = ai2 - ti2;
            ar2 = nar; ai2 = nai;
        }

        // Hermitian unpack (0.5 factors dropped -> pw scaled x4)
        const f2 par2 = bpermv(bpHerm, ar2), pai2 = bpermv(bpHerm, ai2);
        const f2 pbr2 = bpermv(bpHerm, br2), pbi2 = bpermv(bpHerm, bi2);
        const f2 P1r = (lane == 0) ? par2 : pbr2, P1i = (lane == 0) ? pai2 : pbi2;
        const f2 P2r = (lane == 0) ? pbr2 : par2, P2i = (lane == 0) ? pbi2 : pai2;

        f2 Er = ar2 + P1r, Ei = ai2 - P1i;
        f2 Or_ = ar2 - P1r, Oi = ai2 + P1i;
        const f2 X1r = Er + mk2(c1) * Oi - mk2(s1) * Or_;
        const f2 X1i = Ei - mk2(c1) * Or_ - mk2(s1) * Oi;
        const f2 pw1 = X1r * X1r + X1i * X1i;

        Er = br2 + P2r; Ei = bi2 - P2i;
        Or_ = br2 - P2r; Oi = bi2 + P2i;
        const f2 X2r = Er - mk2(s1) * Oi - mk2(c1) * Or_;
        const f2 X2i = Ei + mk2(s1) * Or_ - mk2(c1) * Oi;
        const f2 pw2 = X2r * X2r + X2i * X2i;

        // segmented band reduction
        f2 S1 = pw1, T1 = mk2(a1) * pw1;
        S1 = S1 + ex0v(S1); T1 = T1 + ex0v(T1);
        S1 = S1 + ex1v(S1); T1 = T1 + ex1v(T1);
        S1 = mk2(m8) * ex2v(S1) + S1; T1 = mk2(m8) * ex2v(T1) + T1;
        const f2 D1 = S1 - T1;
        f2 S2 = pw2, T2 = mk2(a2) * pw2;
        S2 = S2 + ex0v(S2); T2 = T2 + ex0v(T2);
        S2 = S2 + ex1v(S2); T2 = T2 + ex1v(T2);
        S2 = S2 + ex2v(S2); T2 = T2 + ex2v(T2);
        S2 = mk2(m16) * ex3v(S2) + S2; T2 = mk2(m16) * ex3v(T2) + T2;
        const f2 D2 = S2 - T2;

        // per-band assembly: band c = A(seg c-1) + D(seg c); edges x2
        const f2 gA1 = bpermv(bpA, T1), gA2 = bpermv(bpA, T2);
        const f2 gD1 = bpermv(bpD, D1), gD2 = bpermv(bpD, D2);
        const f2 A_prev = selA1 ? gA1 : gA2;
        const f2 D_cur  = selD1 ? gD1 : gD2;
        f2 band = A_prev + D_cur;
        if (c == 0)  band = D_cur + D_cur;
        if (c == 21) band = A_prev + A_prev;

        f2 l2;
        l2.x = __log2f(band.x);
        l2.y = __log2f(band.y);

        // lanes 0..31 serve frame0's bands, 32..63 frame1's (permlane lo-broadcast)
        const fpair zsw = bh32(l2.y);
        const float Z = (lane < 32) ? l2.x : zsw.A;

        // symmetric-pair DCT (literal indices, two accumulator chains)
        float acc0 = accInit, acc1 = 0.0f;
        DCTPAIR(0, acc0)  DCTPAIR(1, acc1)
        DCTPAIR(2, acc0)  DCTPAIR(3, acc1)
        DCTPAIR(4, acc0)  DCTPAIR(5, acc1)
        DCTPAIR(6, acc0)  DCTPAIR(7, acc1)
        DCTPAIR(8, acc0)  DCTPAIR(9, acc1)
        DCTPAIR(10, acc0)
        if (oc < NB) *ob = acc0 + acc1;

        // advance
        v0 = nv0; v1 = nv1;
        t0 = nt0; t1 = nt1; p0 = np0; p1 = np1;
        ob += 2 * NB;
    }
}

extern "C" void kernel_launch(void* const* d_in, const int* in_sizes, int n_in,
                              void* d_out, int out_size, void* d_ws, size_t ws_size,
                              hipStream_t stream) {
    const float* x = (const float*)d_in[0];
    float* out = (float*)d_out;
    feat_kernel<<<1792, 256, 0, stream>>>(x, out);
}